// Round 1
// baseline (1004.565 us; speedup 1.0000x reference)
//
#include <hip/hip_runtime.h>
#include <math.h>

// Problem constants (MAB_50921132261692)
#define Bx  4
#define NQx 2048
#define NKx 2048
#define Dx  512
#define Hx  8
#define DSx 64

__device__ __forceinline__ float4 ld4(const float* p){ return *(const float4*)p; }
__device__ __forceinline__ void st4(float* p, float4 v){ *(float4*)p = v; }
__device__ __forceinline__ float dot4(float4 a, float4 b){
  return fmaf(a.x,b.x, fmaf(a.y,b.y, fmaf(a.z,b.z, a.w*b.w)));
}
__device__ __forceinline__ float4 fma4(float a, float4 b, float4 c){
  c.x=fmaf(a,b.x,c.x); c.y=fmaf(a,b.y,c.y); c.z=fmaf(a,b.z,c.z); c.w=fmaf(a,b.w,c.w); return c;
}
__device__ __forceinline__ float4 scl4(float4 a, float s){ a.x*=s; a.y*=s; a.z*=s; a.w*=s; return a; }
__device__ __forceinline__ float red16max(float v){
  v=fmaxf(v,__shfl_xor(v,1)); v=fmaxf(v,__shfl_xor(v,2));
  v=fmaxf(v,__shfl_xor(v,4)); v=fmaxf(v,__shfl_xor(v,8)); return v;
}
__device__ __forceinline__ float red16sum(float v){
  v+=__shfl_xor(v,1); v+=__shfl_xor(v,2); v+=__shfl_xor(v,4); v+=__shfl_xor(v,8); return v;
}

// ---------------------------------------------------------------------------
// C[M,512] = op(A[M,512] @ W[512,512] + bias[512]) (+res). relu applied BEFORE
// residual add (matches reference: O = res + relu(T@W+b)).
// Block tile 64x64, BK=16, 256 threads, 4x4 micro-tile per thread.
// ---------------------------------------------------------------------------
__global__ __launch_bounds__(256) void mab_gemm(
    const float* __restrict__ A, const float* __restrict__ W,
    const float* __restrict__ bias, const float* __restrict__ res,
    float* __restrict__ C, int relu)
{
  const int N = 512, K = 512;
  __shared__ float As[16][68];   // k-major, padded (2-way max -> free)
  __shared__ float Bs[16][64];
  const int m0 = blockIdx.y*64, n0 = blockIdx.x*64;
  const int tid = threadIdx.x, tx = tid&15, ty = tid>>4;
  const int ar = tid>>2, ac4 = tid&3;   // A-tile loader: row ar, float4 #ac4
  const int br = tid>>4, bc4 = tid&15;  // B-tile loader: row br, float4 #bc4
  const float* Ap = A + (size_t)(m0+ar)*K + ac4*4;
  const float* Wp = W + (size_t)br*N + n0 + bc4*4;

  float4 acc0={0,0,0,0}, acc1={0,0,0,0}, acc2={0,0,0,0}, acc3={0,0,0,0};

  for (int k0 = 0; k0 < K; k0 += 16){
    float4 av = ld4(Ap + k0);
    float4 bv = ld4(Wp + (size_t)k0*N);
    __syncthreads();
    As[ac4*4+0][ar]=av.x; As[ac4*4+1][ar]=av.y;
    As[ac4*4+2][ar]=av.z; As[ac4*4+3][ar]=av.w;
    st4(&Bs[br][bc4*4], bv);
    __syncthreads();
    #pragma unroll
    for (int kk=0; kk<16; ++kk){
      float4 a = ld4(&As[kk][ty*4]);
      float4 b = ld4(&Bs[kk][tx*4]);
      acc0 = fma4(a.x,b,acc0); acc1 = fma4(a.y,b,acc1);
      acc2 = fma4(a.z,b,acc2); acc3 = fma4(a.w,b,acc3);
    }
  }

  float4 bb = ld4(bias + n0 + tx*4);
  float4 accs[4] = {acc0,acc1,acc2,acc3};
  #pragma unroll
  for (int i=0;i<4;++i){
    float4 c = accs[i];
    c.x+=bb.x; c.y+=bb.y; c.z+=bb.z; c.w+=bb.w;
    if (relu){ c.x=fmaxf(c.x,0.f); c.y=fmaxf(c.y,0.f); c.z=fmaxf(c.z,0.f); c.w=fmaxf(c.w,0.f); }
    size_t off = (size_t)(m0+ty*4+i)*N + n0 + tx*4;
    if (res){ float4 r = ld4(res+off); c.x+=r.x; c.y+=r.y; c.z+=r.z; c.w+=r.w; }
    st4(C+off, c);
  }
}

// ---------------------------------------------------------------------------
// Fused flash attention + Shaw key/value position biases + residual.
// Grid: (NQ/64, H, B), 256 threads. Per block: 64 q-rows of one head.
// X[b,q, h*64 + d] = Qh + out/l + (akp/l)*vp   (pre-LayerNorm)
// scores = (Qh . Kh)*scale + Kpos*(Qh . kp); online softmax over k.
// ---------------------------------------------------------------------------
__global__ __launch_bounds__(256) void mab_attn(
    const float* __restrict__ Qp, const float* __restrict__ Kp, const float* __restrict__ Vp,
    const float* __restrict__ Kpos, const float* __restrict__ kp, const float* __restrict__ vp,
    float* __restrict__ X)
{
  __shared__ float Qs[64][68];
  __shared__ float Ks[64][68];
  __shared__ float Vs[64][68];
  __shared__ float Ps[64][68];
  __shared__ float qkp_s[64];
  __shared__ float kp_s[64];
  __shared__ float vp_s[64];

  const int q0 = blockIdx.x*64;
  const int h  = blockIdx.y;
  const int b  = blockIdx.z;
  const int tid = threadIdx.x, tx = tid&15, ty = tid>>4;
  const float scale = 0.044194173824159216f;  // 1/sqrt(512)

  const float* Qb  = Qp + ((size_t)(b*NQx + q0))*Dx + h*DSx;
  const float* Kb  = Kp + ((size_t)b*NKx)*Dx + h*DSx;
  const float* Vb  = Vp + ((size_t)b*NKx)*Dx + h*DSx;
  const float* KPb = Kpos + (size_t)b*NQx*NKx;

  if (tid < 64){ kp_s[tid] = kp[tid]; vp_s[tid] = vp[tid]; }
  for (int f = tid; f < 1024; f += 256){
    int r = f>>4, c4 = f&15;
    st4(&Qs[r][c4*4], ld4(Qb + (size_t)r*Dx + c4*4));
  }
  __syncthreads();
  if (tid < 64){
    float s = 0.f;
    #pragma unroll
    for (int d=0; d<64; ++d) s = fmaf(Qs[tid][d], kp_s[d], s);
    qkp_s[tid] = s;   // unscaled Qh . kp  (scale folded into Ks only)
  }

  float m_i[4] = {-1e30f,-1e30f,-1e30f,-1e30f};
  float l_i[4] = {0.f,0.f,0.f,0.f};
  float a_i[4] = {0.f,0.f,0.f,0.f};   // running sum P*Kpos (same rescale as acc)
  float4 acc[4];
  #pragma unroll
  for (int i=0;i<4;++i){ acc[i].x=0.f; acc[i].y=0.f; acc[i].z=0.f; acc[i].w=0.f; }

  for (int kt = 0; kt < NKx/64; ++kt){
    const int k0 = kt*64;
    __syncthreads();   // prev tile fully consumed (also covers qkp_s at kt=0)
    for (int f = tid; f < 1024; f += 256){
      int r = f>>4, c4 = f&15;
      st4(&Ks[r][c4*4], scl4(ld4(Kb + (size_t)(k0+r)*Dx + c4*4), scale));
      st4(&Vs[r][c4*4], ld4(Vb + (size_t)(k0+r)*Dx + c4*4));
    }
    __syncthreads();

    // S = Qs . Ks^T  (Ks pre-scaled)
    float s[4][4];
    #pragma unroll
    for (int i=0;i<4;++i){ s[i][0]=0.f; s[i][1]=0.f; s[i][2]=0.f; s[i][3]=0.f; }
    #pragma unroll 4
    for (int d4=0; d4<16; ++d4){
      float4 q4[4], k4[4];
      #pragma unroll
      for (int i=0;i<4;++i) q4[i]=ld4(&Qs[ty*4+i][d4*4]);
      #pragma unroll
      for (int j=0;j<4;++j) k4[j]=ld4(&Ks[tx*4+j][d4*4]);
      #pragma unroll
      for (int i=0;i<4;++i){
        s[i][0]+=dot4(q4[i],k4[0]); s[i][1]+=dot4(q4[i],k4[1]);
        s[i][2]+=dot4(q4[i],k4[2]); s[i][3]+=dot4(q4[i],k4[3]);
      }
    }

    // + Kpos * qkp (unscaled)
    float4 kpf[4];
    #pragma unroll
    for (int i=0;i<4;++i){
      kpf[i] = ld4(KPb + (size_t)(q0+ty*4+i)*NKx + k0 + tx*4);
      float qk = qkp_s[ty*4+i];
      s[i][0]=fmaf(kpf[i].x,qk,s[i][0]); s[i][1]=fmaf(kpf[i].y,qk,s[i][1]);
      s[i][2]=fmaf(kpf[i].z,qk,s[i][2]); s[i][3]=fmaf(kpf[i].w,qk,s[i][3]);
    }

    // online softmax update per q-row (redundant across the 16 lanes of a row-group)
    #pragma unroll
    for (int i=0;i<4;++i){
      float rm = fmaxf(fmaxf(s[i][0],s[i][1]), fmaxf(s[i][2],s[i][3]));
      rm = red16max(rm);
      float mnew = fmaxf(m_i[i], rm);
      float al = __expf(m_i[i]-mnew); m_i[i]=mnew;
      float p0=__expf(s[i][0]-mnew), p1=__expf(s[i][1]-mnew);
      float p2=__expf(s[i][2]-mnew), p3=__expf(s[i][3]-mnew);
      float rs = red16sum((p0+p1)+(p2+p3));
      float pk = red16sum(fmaf(p0,kpf[i].x, fmaf(p1,kpf[i].y, fmaf(p2,kpf[i].z, p3*kpf[i].w))));
      l_i[i] = fmaf(l_i[i],al,rs);
      a_i[i] = fmaf(a_i[i],al,pk);
      acc[i] = scl4(acc[i],al);
      float4 pp; pp.x=p0; pp.y=p1; pp.z=p2; pp.w=p3;
      st4(&Ps[ty*4+i][tx*4], pp);
    }
    __syncthreads();

    // acc += P @ V
    #pragma unroll 4
    for (int k4=0;k4<16;++k4){
      float4 p4[4];
      #pragma unroll
      for (int i=0;i<4;++i) p4[i]=ld4(&Ps[ty*4+i][k4*4]);
      float4 v;
      v = ld4(&Vs[k4*4+0][tx*4]);
      acc[0]=fma4(p4[0].x,v,acc[0]); acc[1]=fma4(p4[1].x,v,acc[1]);
      acc[2]=fma4(p4[2].x,v,acc[2]); acc[3]=fma4(p4[3].x,v,acc[3]);
      v = ld4(&Vs[k4*4+1][tx*4]);
      acc[0]=fma4(p4[0].y,v,acc[0]); acc[1]=fma4(p4[1].y,v,acc[1]);
      acc[2]=fma4(p4[2].y,v,acc[2]); acc[3]=fma4(p4[3].y,v,acc[3]);
      v = ld4(&Vs[k4*4+2][tx*4]);
      acc[0]=fma4(p4[0].z,v,acc[0]); acc[1]=fma4(p4[1].z,v,acc[1]);
      acc[2]=fma4(p4[2].z,v,acc[2]); acc[3]=fma4(p4[3].z,v,acc[3]);
      v = ld4(&Vs[k4*4+3][tx*4]);
      acc[0]=fma4(p4[0].w,v,acc[0]); acc[1]=fma4(p4[1].w,v,acc[1]);
      acc[2]=fma4(p4[2].w,v,acc[2]); acc[3]=fma4(p4[3].w,v,acc[3]);
    }
  }

  // epilogue: X = Qh + out/l + (akp/l)*vp
  float4 vpv = ld4(&vp_s[tx*4]);
  #pragma unroll
  for (int i=0;i<4;++i){
    float inv = 1.0f/l_i[i];
    float aw = a_i[i]*inv;
    int r = ty*4+i;
    float4 q = ld4(&Qs[r][tx*4]);
    float4 o;
    o.x = q.x + fmaf(acc[i].x,inv, aw*vpv.x);
    o.y = q.y + fmaf(acc[i].y,inv, aw*vpv.y);
    o.z = q.z + fmaf(acc[i].z,inv, aw*vpv.z);
    o.w = q.w + fmaf(acc[i].w,inv, aw*vpv.w);
    st4(X + ((size_t)(b*NQx+q0+r))*Dx + h*DSx + tx*4, o);
  }
}

// ---------------------------------------------------------------------------
// Row LayerNorm over 512 elements. One block (256 thr) per row. In-place safe.
// ---------------------------------------------------------------------------
__global__ __launch_bounds__(256) void mab_ln(
    const float* __restrict__ Xin, const float* __restrict__ g,
    const float* __restrict__ be, float* __restrict__ Y)
{
  const int row = blockIdx.x;
  const int tid = threadIdx.x;
  const float* x = Xin + (size_t)row*Dx;
  float2 v = *(const float2*)(x + tid*2);
  float s  = v.x + v.y;
  float sq = fmaf(v.x,v.x, v.y*v.y);
  #pragma unroll
  for (int m=1; m<64; m<<=1){ s += __shfl_xor(s,m); sq += __shfl_xor(sq,m); }
  __shared__ float red[2][4];
  const int wid = tid>>6, lane = tid&63;
  if (lane==0){ red[0][wid]=s; red[1][wid]=sq; }
  __syncthreads();
  s  = red[0][0]+red[0][1]+red[0][2]+red[0][3];
  sq = red[1][0]+red[1][1]+red[1][2]+red[1][3];
  float mean = s*(1.0f/Dx);
  float var  = sq*(1.0f/Dx) - mean*mean;
  float rstd = rsqrtf(var + 1e-5f);
  float2 gg = *(const float2*)(g  + tid*2);
  float2 bb = *(const float2*)(be + tid*2);
  float2 o;
  o.x = (v.x-mean)*rstd*gg.x + bb.x;
  o.y = (v.y-mean)*rstd*gg.y + bb.y;
  *(float2*)(Y + (size_t)row*Dx + tid*2) = o;
}

// ---------------------------------------------------------------------------
extern "C" void kernel_launch(void* const* d_in, const int* in_sizes, int n_in,
                              void* d_out, int out_size, void* d_ws, size_t ws_size,
                              hipStream_t stream)
{
  const float* Q    = (const float*)d_in[0];
  const float* K    = (const float*)d_in[1];
  const float* Kpos = (const float*)d_in[2];
  const float* Wq   = (const float*)d_in[3];
  const float* bq   = (const float*)d_in[4];
  const float* Wk   = (const float*)d_in[5];
  const float* bk   = (const float*)d_in[6];
  const float* Wv   = (const float*)d_in[7];
  const float* bv   = (const float*)d_in[8];
  const float* kp   = (const float*)d_in[9];
  const float* vp   = (const float*)d_in[10];
  const float* W0   = (const float*)d_in[11];
  const float* b0   = (const float*)d_in[12];
  const float* W1   = (const float*)d_in[13];
  const float* b1   = (const float*)d_in[14];
  const float* g0   = (const float*)d_in[15];
  const float* be0  = (const float*)d_in[16];
  const float* g1   = (const float*)d_in[17];
  const float* be1  = (const float*)d_in[18];
  float* out = (float*)d_out;
  float* ws  = (float*)d_ws;

  const size_t SZ = (size_t)Bx*NQx*Dx;   // 4,194,304 floats per [B,N,512] buffer
  float* Qp = ws;           // proj Q; later reused as T1 (MLP hidden)
  float* Kp = ws + SZ;
  float* Vp = ws + 2*SZ;
  float* O0 = ws + 3*SZ;    // post-LN0 (residual source for fc block)
  // attention pre-LN output X lives in d_out (overwritten later by fc1+LN1)

  dim3 blk(256);
  dim3 gemm_grid(512/64, (Bx*NQx)/64);           // (8, 128)

  mab_gemm<<<gemm_grid, blk, 0, stream>>>(Q, Wq, bq, nullptr, Qp, 0);
  mab_gemm<<<gemm_grid, blk, 0, stream>>>(K, Wk, bk, nullptr, Kp, 0);
  mab_gemm<<<gemm_grid, blk, 0, stream>>>(K, Wv, bv, nullptr, Vp, 0);

  dim3 attn_grid(NQx/64, Hx, Bx);                // (32, 8, 4)
  mab_attn<<<attn_grid, blk, 0, stream>>>(Qp, Kp, Vp, Kpos, kp, vp, out);

  mab_ln<<<dim3(Bx*NQx), blk, 0, stream>>>(out, g0, be0, O0);

  mab_gemm<<<gemm_grid, blk, 0, stream>>>(O0, W0, b0, nullptr, Qp, 1);   // T1=relu(O0@W0+b0)
  mab_gemm<<<gemm_grid, blk, 0, stream>>>(Qp, W1, b1, O0,     out, 1);   // T2=O0+relu(T1@W1+b1)

  mab_ln<<<dim3(Bx*NQx), blk, 0, stream>>>(out, g1, be1, out);           // final LN in-place
}

// Round 2
// 278.683 us; speedup vs baseline: 3.6047x; 3.6047x over previous
//
#include <hip/hip_runtime.h>
#include <math.h>

// Problem constants (MAB_50921132261692)
#define Bx  4
#define NQx 2048
#define NKx 2048
#define Dx  512
#define Hx  8

typedef __attribute__((ext_vector_type(8))) __bf16 bf16x8;
typedef __attribute__((ext_vector_type(4))) float f32x4;

typedef const __attribute__((address_space(1))) unsigned int* gas_ptr;
typedef __attribute__((address_space(3))) unsigned int* lds_ptr;

__device__ __forceinline__ void gload16(const void* g, void* l){
  __builtin_amdgcn_global_load_lds((gas_ptr)g, (lds_ptr)l, 16, 0, 0);
}

__device__ __forceinline__ unsigned short f2bf(float f){
  union { float f; unsigned int u; } v; v.f = f;
  unsigned int r = (v.u + 0x7FFFu + ((v.u >> 16) & 1u)) >> 16;
  return (unsigned short)r;
}
__device__ __forceinline__ float bf2f(unsigned short u){
  union { unsigned int u; float f; } v; v.u = ((unsigned int)u) << 16; return v.f;
}

// ---------------------------------------------------------------------------
// f32 -> bf16 convert for two tensors (Q and K), grid-stride over float4s.
// ---------------------------------------------------------------------------
__global__ __launch_bounds__(256) void mab_cvt(
    const float* __restrict__ S0, unsigned short* __restrict__ D0,
    const float* __restrict__ S1, unsigned short* __restrict__ D1, int n4each)
{
  int total = n4each*2;
  for (int i = blockIdx.x*blockDim.x + threadIdx.x; i < total; i += gridDim.x*blockDim.x){
    const float* S; unsigned short* D; int j;
    if (i < n4each){ S = S0; D = D0; j = i; } else { S = S1; D = D1; j = i - n4each; }
    float4 v = ((const float4*)S)[j];
    ushort4 o; o.x=f2bf(v.x); o.y=f2bf(v.y); o.z=f2bf(v.z); o.w=f2bf(v.w);
    ((ushort4*)D)[j] = o;
  }
}

// ---------------------------------------------------------------------------
// Transpose + convert 5 weights [512][512] f32 -> Wt bf16 [z][N=512][K=512].
// ---------------------------------------------------------------------------
__global__ __launch_bounds__(256) void mab_wt(
    const float* __restrict__ Wq, const float* __restrict__ Wk, const float* __restrict__ Wv,
    const float* __restrict__ W0, const float* __restrict__ W1,
    unsigned short* __restrict__ Wt)
{
  __shared__ unsigned short T[64][72];
  const int z = blockIdx.z;
  const float* W = (z==0)?Wq:(z==1)?Wk:(z==2)?Wv:(z==3)?W0:W1;
  unsigned short* O = Wt + (size_t)z*512*512;
  const int k0 = blockIdx.x*64, n0 = blockIdx.y*64;
  const int tid = threadIdx.x;
  #pragma unroll
  for (int i=0;i<4;++i){
    int id = tid + i*256;          // 1024 = 64 rows x 16 float4
    int r = id>>4, c4 = id&15;
    float4 v = *(const float4*)(W + (size_t)(k0+r)*512 + n0 + c4*4);
    ushort4 o; o.x=f2bf(v.x); o.y=f2bf(v.y); o.z=f2bf(v.z); o.w=f2bf(v.w);
    *(ushort4*)&T[r][c4*4] = o;
  }
  __syncthreads();
  #pragma unroll
  for (int i=0;i<2;++i){
    int id = tid + i*256;          // 512 = 64 out-rows x 8 chunks
    int c = id>>3, r8 = id&7;
    union { unsigned short u[8]; uint4 v; } o;
    #pragma unroll
    for (int j=0;j<8;++j) o.u[j] = T[r8*8+j][c];
    *(uint4*)(O + (size_t)(n0+c)*512 + k0 + r8*8) = o.v;
  }
}

// ---------------------------------------------------------------------------
// Transpose Vp bf16 [B*NK][512] -> Vpt [B][512][NK] (d-major per batch).
// ---------------------------------------------------------------------------
__global__ __launch_bounds__(256) void mab_vt(
    const unsigned short* __restrict__ Vp, unsigned short* __restrict__ Vpt)
{
  __shared__ unsigned short T[64][72];
  const int r0 = blockIdx.x*64;   // k within batch
  const int c0 = blockIdx.y*64;   // d
  const int b  = blockIdx.z;
  const int tid = threadIdx.x;
  #pragma unroll
  for (int i=0;i<2;++i){
    int id = tid + i*256;          // 512 = 64 rows x 8 chunks(8 bf16)
    int r = id>>3, c8 = id&7;
    *(uint4*)&T[r][c8*8] = *(const uint4*)(Vp + (size_t)(b*NKx + r0+r)*512 + c0 + c8*8);
  }
  __syncthreads();
  #pragma unroll
  for (int i=0;i<2;++i){
    int id = tid + i*256;
    int c = id>>3, r8 = id&7;
    union { unsigned short u[8]; uint4 v; } o;
    #pragma unroll
    for (int j=0;j<8;++j) o.u[j] = T[r8*8+j][c];
    *(uint4*)(Vpt + ((size_t)(b*512) + c0 + c)*NKx + r0 + r8*8) = o.v;
  }
}

// ---------------------------------------------------------------------------
// bf16 MFMA GEMM: C[M,512] = op(A[M,512] @ Wt^T + bias) (+res)
// A row-major bf16 [M][512]; Wt row-major bf16 [512 n][512 k].
// 128x128 tile, BK=64, 4 waves (2x2), 4x4 16x16 frags per wave.
// global_load_lds staging with XOR chunk pre-swizzle (linear LDS dest,
// inverse-swizzled global source, swizzled read — both-sides involution).
// ---------------------------------------------------------------------------
__global__ __launch_bounds__(256) void mab_gemm_mfma(
    const unsigned short* __restrict__ A0, const unsigned short* __restrict__ A1,
    const unsigned short* __restrict__ Wt,
    const float* __restrict__ bias0, const float* __restrict__ bias1, const float* __restrict__ bias2,
    const float* __restrict__ res,
    unsigned short* __restrict__ Cb, float* __restrict__ Cf,
    int relu, float scaleArg, size_t zstride)
{
  __shared__ unsigned short As[128][64];
  __shared__ unsigned short Bs[128][64];
  const int z = blockIdx.z;
  const unsigned short* A = (z == 0) ? A0 : A1;
  const unsigned short* W = Wt + (size_t)z*512*512;
  const float* bias = (z==0)?bias0:((z==1)?bias1:bias2);
  const float sc = (z==1) ? scaleArg : 1.0f;
  const int m0 = blockIdx.y*128, n0 = blockIdx.x*128;
  const int tid = threadIdx.x, w = tid>>6, lane = tid&63, g = lane>>4, q16 = lane&15;
  const int wr = w>>1, wc = w&1;

  f32x4 acc[4][4];
  #pragma unroll
  for (int m=0;m<4;++m)
    #pragma unroll
    for (int n=0;n<4;++n) acc[m][n] = (f32x4){0.f,0.f,0.f,0.f};

  for (int k0 = 0; k0 < 512; k0 += 64){
    __syncthreads();
    #pragma unroll
    for (int i=0;i<4;++i){
      int o   = (w*4 + i)*1024 + lane*16;    // byte offset in 16KB tile
      int row = o >> 7;
      int c   = (o >> 4) & 7;
      int cs  = c ^ (row & 7);
      gload16(A + (size_t)(m0+row)*512 + k0 + cs*8, (char*)&As[0][0] + (w*4+i)*1024);
      gload16(W + (size_t)(n0+row)*512 + k0 + cs*8, (char*)&Bs[0][0] + (w*4+i)*1024);
    }
    __syncthreads();
    #pragma unroll
    for (int ks=0;ks<2;++ks){
      bf16x8 af[4], bfr[4];
      #pragma unroll
      for (int m=0;m<4;++m){
        int row = wr*64 + m*16 + q16;
        int c   = (ks*4 + g) ^ (row & 7);
        af[m] = *(const bf16x8*)((const char*)&As[0][0] + row*128 + c*16);
      }
      #pragma unroll
      for (int n=0;n<4;++n){
        int row = wc*64 + n*16 + q16;
        int c   = (ks*4 + g) ^ (row & 7);
        bfr[n] = *(const bf16x8*)((const char*)&Bs[0][0] + row*128 + c*16);
      }
      #pragma unroll
      for (int m=0;m<4;++m)
        #pragma unroll
        for (int n=0;n<4;++n)
          acc[m][n] = __builtin_amdgcn_mfma_f32_16x16x32_bf16(af[m], bfr[n], acc[m][n], 0,0,0);
    }
  }

  // epilogue: C row = m0 + wr*64 + m*16 + g*4 + r; col = n0 + wc*64 + n*16 + q16
  #pragma unroll
  for (int m=0;m<4;++m){
    const int rowl = wr*64 + m*16 + g*4;
    #pragma unroll
    for (int n=0;n<4;++n){
      const int col = n0 + wc*64 + n*16 + q16;
      const float bv = bias[col];
      #pragma unroll
      for (int r=0;r<4;++r){
        float v = acc[m][n][r] + bv;
        if (relu) v = fmaxf(v, 0.f);
        v *= sc;
        size_t off = (size_t)(m0 + rowl + r)*512 + col;
        if (res) v += res[off];
        if (Cb) Cb[(size_t)z*zstride + off] = f2bf(v);
        if (Cf) Cf[off] = v;
      }
    }
  }
}

// ---------------------------------------------------------------------------
// MFMA flash attention + Shaw key/value position biases + residual.
// Grid (NQ/64, H, B), 256 thr = 4 waves x 16 q-rows.
// Kp pre-scaled by 1/sqrt(512). Vpt is d-major [B][512][NK].
// X = Qh + out/l + (akp/l)*vp   (pre-LayerNorm), f32.
// ---------------------------------------------------------------------------
__global__ __launch_bounds__(256) void mab_attn_mfma(
    const unsigned short* __restrict__ Qp, const unsigned short* __restrict__ Kp,
    const unsigned short* __restrict__ Vpt,
    const float* __restrict__ Kpos, const float* __restrict__ kp, const float* __restrict__ vp,
    float* __restrict__ X)
{
  __shared__ unsigned short Qs[64][72];   // [q][d]
  __shared__ unsigned short Ks[64][72];   // [k][d]
  __shared__ unsigned short Vts[64][72];  // [d][k]
  __shared__ unsigned short Ps[4][16][72];// per-wave [q][k]

  const int q0 = blockIdx.x*64;
  const int h  = blockIdx.y;
  const int b  = blockIdx.z;
  const int tid = threadIdx.x, w = tid>>6, lane = tid&63, g = lane>>4, q16 = lane&15;

  const unsigned short* Qg = Qp + ((size_t)(b*NQx + q0))*Dx + h*64;
  const unsigned short* Kg = Kp + ((size_t)b*NKx)*Dx + h*64;
  const unsigned short* Vg = Vpt + ((size_t)(b*512) + h*64)*NKx;
  const float* KPg = Kpos + (size_t)b*NQx*NKx + (size_t)q0*NKx;

  // stage Q tile (64 rows x 64 d)
  #pragma unroll
  for (int i=0;i<2;++i){
    int id = tid + i*256;
    int r = id>>3, c8 = id&7;
    *(uint4*)&Qs[r][c8*8] = *(const uint4*)(Qg + (size_t)r*Dx + c8*8);
  }
  __syncthreads();

  // hoist Q A-frags (wave rows w*16 .. w*16+15)
  bf16x8 qf[2];
  #pragma unroll
  for (int ks=0;ks<2;++ks)
    qf[ks] = *(const bf16x8*)&Qs[w*16 + q16][ks*32 + g*8];

  // qkp = Qh . kp (unscaled), per q-row
  float qkp_part = 0.f;
  #pragma unroll
  for (int ks=0;ks<2;++ks){
    union { bf16x8 v; unsigned short u[8]; } qa; qa.v = qf[ks];
    #pragma unroll
    for (int j=0;j<8;++j)
      qkp_part = fmaf(bf2f(qa.u[j]), kp[ks*32 + g*8 + j], qkp_part);
  }
  qkp_part += __shfl_xor(qkp_part, 16);
  qkp_part += __shfl_xor(qkp_part, 32);   // all lanes: qkp of row q16
  float qkp_r[4];
  #pragma unroll
  for (int r=0;r<4;++r) qkp_r[r] = __shfl(qkp_part, g*4 + r);

  float m_i[4], l_i[4], a_i[4];
  f32x4 accO[4];
  #pragma unroll
  for (int r=0;r<4;++r){ m_i[r] = -3.0e38f; l_i[r] = 0.f; a_i[r] = 0.f; }
  #pragma unroll
  for (int n=0;n<4;++n) accO[n] = (f32x4){0.f,0.f,0.f,0.f};

  for (int k0 = 0; k0 < NKx; k0 += 64){
    __syncthreads();
    #pragma unroll
    for (int i=0;i<2;++i){
      int id = tid + i*256;
      int r = id>>3, c8 = id&7;
      *(uint4*)&Ks[r][c8*8]  = *(const uint4*)(Kg + (size_t)(k0+r)*Dx + c8*8);
      *(uint4*)&Vts[r][c8*8] = *(const uint4*)(Vg + (size_t)r*NKx + k0 + c8*8);
    }
    __syncthreads();

    // S = Q . K^T (Kp pre-scaled)
    f32x4 sf[4];
    #pragma unroll
    for (int n=0;n<4;++n){
      f32x4 c = (f32x4){0.f,0.f,0.f,0.f};
      #pragma unroll
      for (int ks=0;ks<2;++ks){
        bf16x8 kf = *(const bf16x8*)&Ks[n*16 + q16][ks*32 + g*8];
        c = __builtin_amdgcn_mfma_f32_16x16x32_bf16(qf[ks], kf, c, 0,0,0);
      }
      sf[n] = c;
    }

    // + Kpos * qkp
    float kpf[4][4];
    #pragma unroll
    for (int n=0;n<4;++n){
      #pragma unroll
      for (int r=0;r<4;++r){
        kpf[n][r] = KPg[(size_t)(w*16 + g*4 + r)*NKx + k0 + n*16 + q16];
        sf[n][r] = fmaf(kpf[n][r], qkp_r[r], sf[n][r]);
      }
    }

    // online softmax per row (4 rows/lane), 16-lane reductions
    #pragma unroll
    for (int r=0;r<4;++r){
      float rm = fmaxf(fmaxf(sf[0][r], sf[1][r]), fmaxf(sf[2][r], sf[3][r]));
      rm = fmaxf(rm, __shfl_xor(rm, 1));
      rm = fmaxf(rm, __shfl_xor(rm, 2));
      rm = fmaxf(rm, __shfl_xor(rm, 4));
      rm = fmaxf(rm, __shfl_xor(rm, 8));
      float mnew = fmaxf(m_i[r], rm);
      float al = __expf(m_i[r] - mnew);
      m_i[r] = mnew;
      float p0 = __expf(sf[0][r]-mnew), p1 = __expf(sf[1][r]-mnew);
      float p2 = __expf(sf[2][r]-mnew), p3 = __expf(sf[3][r]-mnew);
      float ps = (p0+p1)+(p2+p3);
      float pk = fmaf(p0,kpf[0][r], fmaf(p1,kpf[1][r], fmaf(p2,kpf[2][r], p3*kpf[3][r])));
      ps += __shfl_xor(ps,1); ps += __shfl_xor(ps,2);
      ps += __shfl_xor(ps,4); ps += __shfl_xor(ps,8);
      pk += __shfl_xor(pk,1); pk += __shfl_xor(pk,2);
      pk += __shfl_xor(pk,4); pk += __shfl_xor(pk,8);
      l_i[r] = fmaf(l_i[r], al, ps);
      a_i[r] = fmaf(a_i[r], al, pk);
      #pragma unroll
      for (int n=0;n<4;++n) accO[n][r] *= al;
      Ps[w][g*4+r][0*16 + q16] = f2bf(p0);
      Ps[w][g*4+r][1*16 + q16] = f2bf(p1);
      Ps[w][g*4+r][2*16 + q16] = f2bf(p2);
      Ps[w][g*4+r][3*16 + q16] = f2bf(p3);
    }

    // O += P @ V  (Ps wave-private: no barrier needed, in-wave LDS ordering)
    #pragma unroll
    for (int ks=0;ks<2;++ks){
      bf16x8 pf = *(const bf16x8*)&Ps[w][q16][ks*32 + g*8];
      #pragma unroll
      for (int n=0;n<4;++n){
        bf16x8 vf = *(const bf16x8*)&Vts[n*16 + q16][ks*32 + g*8];
        accO[n] = __builtin_amdgcn_mfma_f32_16x16x32_bf16(pf, vf, accO[n], 0,0,0);
      }
    }
  }

  // epilogue: X = Qh + O/l + (akp/l)*vp
  #pragma unroll
  for (int r=0;r<4;++r){
    float inv = 1.0f / l_i[r];
    float aw  = a_i[r] * inv;
    int qloc = w*16 + g*4 + r;
    float* Xrow = X + ((size_t)(b*NQx + q0 + qloc))*Dx + h*64;
    #pragma unroll
    for (int n=0;n<4;++n){
      int d = n*16 + q16;
      float o = accO[n][r]*inv + bf2f(Qs[qloc][d]) + aw*vp[d];
      Xrow[d] = o;
    }
  }
}

// ---------------------------------------------------------------------------
// Row LayerNorm over 512; optional secondary bf16 output.
// ---------------------------------------------------------------------------
__global__ __launch_bounds__(256) void mab_ln2(
    const float* __restrict__ Xin, const float* __restrict__ g,
    const float* __restrict__ be, float* __restrict__ Yf, unsigned short* __restrict__ Yb)
{
  const int row = blockIdx.x;
  const int tid = threadIdx.x;
  const float* x = Xin + (size_t)row*Dx;
  float2 v = *(const float2*)(x + tid*2);
  float s  = v.x + v.y;
  float sq = fmaf(v.x,v.x, v.y*v.y);
  #pragma unroll
  for (int m=1; m<64; m<<=1){ s += __shfl_xor(s,m); sq += __shfl_xor(sq,m); }
  __shared__ float red[2][4];
  const int wid = tid>>6, lane = tid&63;
  if (lane==0){ red[0][wid]=s; red[1][wid]=sq; }
  __syncthreads();
  s  = red[0][0]+red[0][1]+red[0][2]+red[0][3];
  sq = red[1][0]+red[1][1]+red[1][2]+red[1][3];
  float mean = s*(1.0f/Dx);
  float var  = sq*(1.0f/Dx) - mean*mean;
  float rstd = rsqrtf(var + 1e-5f);
  float2 gg = *(const float2*)(g  + tid*2);
  float2 bb = *(const float2*)(be + tid*2);
  float2 o;
  o.x = (v.x-mean)*rstd*gg.x + bb.x;
  o.y = (v.y-mean)*rstd*gg.y + bb.y;
  if (Yf) *(float2*)(Yf + (size_t)row*Dx + tid*2) = o;
  if (Yb){
    ushort2 ob; ob.x = f2bf(o.x); ob.y = f2bf(o.y);
    *(ushort2*)(Yb + (size_t)row*Dx + tid*2) = ob;
  }
}

// ---------------------------------------------------------------------------
extern "C" void kernel_launch(void* const* d_in, const int* in_sizes, int n_in,
                              void* d_out, int out_size, void* d_ws, size_t ws_size,
                              hipStream_t stream)
{
  const float* Q    = (const float*)d_in[0];
  const float* K    = (const float*)d_in[1];
  const float* Kpos = (const float*)d_in[2];
  const float* Wq   = (const float*)d_in[3];
  const float* bq   = (const float*)d_in[4];
  const float* Wk   = (const float*)d_in[5];
  const float* bk   = (const float*)d_in[6];
  const float* Wv   = (const float*)d_in[7];
  const float* bv   = (const float*)d_in[8];
  const float* kp   = (const float*)d_in[9];
  const float* vp   = (const float*)d_in[10];
  const float* W0   = (const float*)d_in[11];
  const float* b0   = (const float*)d_in[12];
  const float* W1   = (const float*)d_in[13];
  const float* b1   = (const float*)d_in[14];
  const float* g0   = (const float*)d_in[15];
  const float* be0  = (const float*)d_in[16];
  const float* g1   = (const float*)d_in[17];
  const float* be1  = (const float*)d_in[18];
  float* out = (float*)d_out;
  char* wsb  = (char*)d_ws;

  const size_t MB = 1024*1024;
  unsigned short* Qp  = (unsigned short*)(wsb);          // 8 MiB  [8192][512] bf16
  unsigned short* Kp  = (unsigned short*)(wsb + 8*MB);   // pre-scaled
  unsigned short* Vp  = (unsigned short*)(wsb + 16*MB);
  float*          O0  = (float*)         (wsb + 24*MB);  // 16 MiB f32
  unsigned short* Qb  = (unsigned short*)(wsb + 40*MB);  // 8 MiB -> Vpt after proj
  unsigned short* Kb  = (unsigned short*)(wsb + 48*MB);  // 8 MiB -> O0b after proj
  unsigned short* Wt  = (unsigned short*)(wsb + 56*MB);  // 2.5 MiB [5][512][512]
  unsigned short* Vpt = Qb;
  unsigned short* O0b = Kb;
  unsigned short* T1  = Vp;

  const float scale = 0.044194173824159216f;   // 1/sqrt(512)
  const size_t ZS = (size_t)8192*512;

  // bf16 conversions of Q, K
  mab_cvt<<<2048, 256, 0, stream>>>(Q, Qb, K, Kb, (8192*512)/4);
  // weight transposes (Wq,Wk,Wv,W0,W1)
  mab_wt<<<dim3(8,8,5), 256, 0, stream>>>(Wq, Wk, Wv, W0, W1, Wt);
  // fused Q/K/V projections (z=0,1,2); Kp scaled by 1/sqrt(512)
  mab_gemm_mfma<<<dim3(4,64,3), 256, 0, stream>>>(
      Qb, Kb, Wt, bq, bk, bv, nullptr, Qp, nullptr, 0, scale, ZS);
  // V transpose to d-major
  mab_vt<<<dim3(32,8,4), 256, 0, stream>>>(Vp, Vpt);
  // fused attention
  mab_attn_mfma<<<dim3(32,8,4), 256, 0, stream>>>(Qp, Kp, Vpt, Kpos, kp, vp, out);
  // LN0 -> O0 (f32) + O0b (bf16)
  mab_ln2<<<8192, 256, 0, stream>>>(out, g0, be0, O0, O0b);
  // T1 = relu(O0 @ W0 + b0)  (bf16 out)
  mab_gemm_mfma<<<dim3(4,64,1), 256, 0, stream>>>(
      O0b, nullptr, Wt + (size_t)3*512*512, b0, b0, b0, nullptr, T1, nullptr, 1, 1.0f, 0);
  // out = O0 + relu(T1 @ W1 + b1)  (f32 out)
  mab_gemm_mfma<<<dim3(4,64,1), 256, 0, stream>>>(
      T1, nullptr, Wt + (size_t)4*512*512, b1, b1, b1, O0, nullptr, out, 1, 1.0f, 0);
  // final LN in-place
  mab_ln2<<<8192, 256, 0, stream>>>(out, g1, be1, out, nullptr);
}

// Round 3
// 204.235 us; speedup vs baseline: 4.9187x; 1.3645x over previous
//
#include <hip/hip_runtime.h>
#include <math.h>

// Problem constants (MAB_50921132261692)
#define Bx  4
#define NQx 2048
#define NKx 2048
#define Dx  512
#define Hx  8

typedef __attribute__((ext_vector_type(8))) __bf16 bf16x8;
typedef __attribute__((ext_vector_type(4))) float f32x4;
typedef __attribute__((ext_vector_type(16))) float f32x16;

typedef const __attribute__((address_space(1))) unsigned int* gas_ptr;
typedef __attribute__((address_space(3))) unsigned int* lds_ptr;

__device__ __forceinline__ void gload16(const void* g, void* l){
  __builtin_amdgcn_global_load_lds((gas_ptr)g, (lds_ptr)l, 16, 0, 0);
}

__device__ __forceinline__ unsigned short f2bf(float f){
  union { float f; unsigned int u; } v; v.f = f;
  unsigned int r = (v.u + 0x7FFFu + ((v.u >> 16) & 1u)) >> 16;
  return (unsigned short)r;
}
__device__ __forceinline__ float bf2f(unsigned short u){
  union { unsigned int u; float f; } v; v.u = ((unsigned int)u) << 16; return v.f;
}
__device__ __forceinline__ unsigned int cvtpk_bf16(float a, float b){
  unsigned int d;
  asm("v_cvt_pk_bf16_f32 %0, %1, %2" : "=v"(d) : "v"(a), "v"(b));
  return d;
}
__device__ __forceinline__ void plane32_swap(unsigned int& a, unsigned int& b){
  asm("v_permlane32_swap_b32 %0, %1" : "+v"(a), "+v"(b));
}

// ---------------------------------------------------------------------------
// f32 -> bf16 convert for two tensors (Q and K), grid-stride over float4s.
// ---------------------------------------------------------------------------
__global__ __launch_bounds__(256) void mab_cvt(
    const float* __restrict__ S0, unsigned short* __restrict__ D0,
    const float* __restrict__ S1, unsigned short* __restrict__ D1, int n4each)
{
  int total = n4each*2;
  for (int i = blockIdx.x*blockDim.x + threadIdx.x; i < total; i += gridDim.x*blockDim.x){
    const float* S; unsigned short* D; int j;
    if (i < n4each){ S = S0; D = D0; j = i; } else { S = S1; D = D1; j = i - n4each; }
    float4 v = ((const float4*)S)[j];
    ushort4 o; o.x=f2bf(v.x); o.y=f2bf(v.y); o.z=f2bf(v.z); o.w=f2bf(v.w);
    ((ushort4*)D)[j] = o;
  }
}

// ---------------------------------------------------------------------------
// Transpose + convert 5 weights [512][512] f32 -> Wt bf16 [z][N=512][K=512].
// ---------------------------------------------------------------------------
__global__ __launch_bounds__(256) void mab_wt(
    const float* __restrict__ Wq, const float* __restrict__ Wk, const float* __restrict__ Wv,
    const float* __restrict__ W0, const float* __restrict__ W1,
    unsigned short* __restrict__ Wt)
{
  __shared__ unsigned short T[64][72];
  const int z = blockIdx.z;
  const float* W = (z==0)?Wq:(z==1)?Wk:(z==2)?Wv:(z==3)?W0:W1;
  unsigned short* O = Wt + (size_t)z*512*512;
  const int k0 = blockIdx.x*64, n0 = blockIdx.y*64;
  const int tid = threadIdx.x;
  #pragma unroll
  for (int i=0;i<4;++i){
    int id = tid + i*256;          // 1024 = 64 rows x 16 float4
    int r = id>>4, c4 = id&15;
    float4 v = *(const float4*)(W + (size_t)(k0+r)*512 + n0 + c4*4);
    ushort4 o; o.x=f2bf(v.x); o.y=f2bf(v.y); o.z=f2bf(v.z); o.w=f2bf(v.w);
    *(ushort4*)&T[r][c4*4] = o;
  }
  __syncthreads();
  #pragma unroll
  for (int i=0;i<2;++i){
    int id = tid + i*256;          // 512 = 64 out-rows x 8 chunks
    int c = id>>3, r8 = id&7;
    union { unsigned short u[8]; uint4 v; } o;
    #pragma unroll
    for (int j=0;j<8;++j) o.u[j] = T[r8*8+j][c];
    *(uint4*)(O + (size_t)(n0+c)*512 + k0 + r8*8) = o.v;
  }
}

// ---------------------------------------------------------------------------
// Transpose Vp bf16 [B*NK][512] -> Vpt [B][512][NK] (d-major per batch).
// ---------------------------------------------------------------------------
__global__ __launch_bounds__(256) void mab_vt(
    const unsigned short* __restrict__ Vp, unsigned short* __restrict__ Vpt)
{
  __shared__ unsigned short T[64][72];
  const int r0 = blockIdx.x*64;   // k within batch
  const int c0 = blockIdx.y*64;   // d
  const int b  = blockIdx.z;
  const int tid = threadIdx.x;
  #pragma unroll
  for (int i=0;i<2;++i){
    int id = tid + i*256;          // 512 = 64 rows x 8 chunks(8 bf16)
    int r = id>>3, c8 = id&7;
    *(uint4*)&T[r][c8*8] = *(const uint4*)(Vp + (size_t)(b*NKx + r0+r)*512 + c0 + c8*8);
  }
  __syncthreads();
  #pragma unroll
  for (int i=0;i<2;++i){
    int id = tid + i*256;
    int c = id>>3, r8 = id&7;
    union { unsigned short u[8]; uint4 v; } o;
    #pragma unroll
    for (int j=0;j<8;++j) o.u[j] = T[r8*8+j][c];
    *(uint4*)(Vpt + ((size_t)(b*512) + c0 + c)*NKx + r0 + r8*8) = o.v;
  }
}

// ---------------------------------------------------------------------------
// bf16 MFMA GEMM: C[M,512] = op(A[M,512] @ Wt^T + bias) (+res)
// 128x128 tile, BK=64, 4 waves (2x2), 4x4 16x16 frags per wave.
// ---------------------------------------------------------------------------
__global__ __launch_bounds__(256) void mab_gemm_mfma(
    const unsigned short* __restrict__ A0, const unsigned short* __restrict__ A1,
    const unsigned short* __restrict__ Wt,
    const float* __restrict__ bias0, const float* __restrict__ bias1, const float* __restrict__ bias2,
    const float* __restrict__ res,
    unsigned short* __restrict__ Cb, float* __restrict__ Cf,
    int relu, float scaleArg, size_t zstride)
{
  __shared__ unsigned short As[128][64];
  __shared__ unsigned short Bs[128][64];
  const int z = blockIdx.z;
  const unsigned short* A = (z == 0) ? A0 : A1;
  const unsigned short* W = Wt + (size_t)z*512*512;
  const float* bias = (z==0)?bias0:((z==1)?bias1:bias2);
  const float sc = (z==1) ? scaleArg : 1.0f;
  const int m0 = blockIdx.y*128, n0 = blockIdx.x*128;
  const int tid = threadIdx.x, w = tid>>6, lane = tid&63, g = lane>>4, q16 = lane&15;
  const int wr = w>>1, wc = w&1;

  f32x4 acc[4][4];
  #pragma unroll
  for (int m=0;m<4;++m)
    #pragma unroll
    for (int n=0;n<4;++n) acc[m][n] = (f32x4){0.f,0.f,0.f,0.f};

  for (int k0 = 0; k0 < 512; k0 += 64){
    __syncthreads();
    #pragma unroll
    for (int i=0;i<4;++i){
      int o   = (w*4 + i)*1024 + lane*16;    // byte offset in 16KB tile
      int row = o >> 7;
      int c   = (o >> 4) & 7;
      int cs  = c ^ (row & 7);
      gload16(A + (size_t)(m0+row)*512 + k0 + cs*8, (char*)&As[0][0] + (w*4+i)*1024);
      gload16(W + (size_t)(n0+row)*512 + k0 + cs*8, (char*)&Bs[0][0] + (w*4+i)*1024);
    }
    __syncthreads();
    #pragma unroll
    for (int ks=0;ks<2;++ks){
      bf16x8 af[4], bfr[4];
      #pragma unroll
      for (int m=0;m<4;++m){
        int row = wr*64 + m*16 + q16;
        int c   = (ks*4 + g) ^ (row & 7);
        af[m] = *(const bf16x8*)((const char*)&As[0][0] + row*128 + c*16);
      }
      #pragma unroll
      for (int n=0;n<4;++n){
        int row = wc*64 + n*16 + q16;
        int c   = (ks*4 + g) ^ (row & 7);
        bfr[n] = *(const bf16x8*)((const char*)&Bs[0][0] + row*128 + c*16);
      }
      #pragma unroll
      for (int m=0;m<4;++m)
        #pragma unroll
        for (int n=0;n<4;++n)
          acc[m][n] = __builtin_amdgcn_mfma_f32_16x16x32_bf16(af[m], bfr[n], acc[m][n], 0,0,0);
    }
  }

  #pragma unroll
  for (int m=0;m<4;++m){
    const int rowl = wr*64 + m*16 + g*4;
    #pragma unroll
    for (int n=0;n<4;++n){
      const int col = n0 + wc*64 + n*16 + q16;
      const float bv = bias[col];
      #pragma unroll
      for (int r=0;r<4;++r){
        float v = acc[m][n][r] + bv;
        if (relu) v = fmaxf(v, 0.f);
        v *= sc;
        size_t off = (size_t)(m0 + rowl + r)*512 + col;
        if (res) v += res[off];
        if (Cb) Cb[(size_t)z*zstride + off] = f2bf(v);
        if (Cf) Cf[off] = v;
      }
    }
  }
}

// ---------------------------------------------------------------------------
// MFMA flash attention, 32x32 swapped-operand structure.
// Grid (NQ/128, H, B), 4 waves x 32 q-rows. KVBLK=64, double-buffered K/V
// via global_load_lds + XOR swizzle. P kept in registers (cvt_pk +
// permlane32_swap). Online softmax with defer-max (THR=8).
// Kp pre-scaled by 1/sqrt(512). Vpt is d-major [B][512][NK].
// X = Qh + O/l + (akp/l)*vp   (pre-LayerNorm), f32.
// ---------------------------------------------------------------------------
__global__ __launch_bounds__(256) void mab_attn2(
    const unsigned short* __restrict__ Qp, const unsigned short* __restrict__ Kp,
    const unsigned short* __restrict__ Vpt,
    const float* __restrict__ Kpos, const float* __restrict__ kp, const float* __restrict__ vp,
    float* __restrict__ X)
{
  __shared__ unsigned short Kb[2][64][64];   // [k'][d], swizzled chunks
  __shared__ unsigned short Vb[2][64][64];   // [d][k'], swizzled chunks
  __shared__ unsigned short Qs[128][72];     // [q][d], padded

  const int q0 = blockIdx.x*128;
  const int h  = blockIdx.y;
  const int b  = blockIdx.z;
  const int tid = threadIdx.x, w = tid>>6, lane = tid&63;
  const int q32 = lane & 31, hi = lane >> 5;

  const unsigned short* Qg = Qp + ((size_t)(b*NQx + q0))*Dx + h*64;
  const unsigned short* Kg = Kp + ((size_t)b*NKx)*Dx + h*64;
  const unsigned short* Vg = Vpt + ((size_t)(b*512) + h*64)*NKx;
  const float* KProw = Kpos + (size_t)b*NQx*NKx + (size_t)(q0 + w*32 + q32)*NKx;

  // staging geometry (per wave: 16 rows of each tile; linear LDS dest)
  const int sr = lane>>3;        // 0..7
  const int sc = lane&7;         // chunk 0..7

  // prologue: stage K/V tile 0, stage Q
  #pragma unroll
  for (int i=0;i<2;++i){
    int r  = i*8 + sr;                 // local row 0..15 (tile row w*16+r)
    int cs = sc ^ (r & 7);
    gload16(Kg + (size_t)(w*16 + r)*Dx + cs*8, (char*)&Kb[0][0][0] + w*2048 + i*1024);
    gload16(Vg + (size_t)(w*16 + r)*NKx + cs*8, (char*)&Vb[0][0][0] + w*2048 + i*1024);
  }
  #pragma unroll
  for (int i=0;i<4;++i){
    int id = tid + i*256;              // 1024 = 128 rows x 8 chunks
    int r = id>>3, c8 = id&7;
    *(uint4*)&Qs[r][c8*8] = *(const uint4*)(Qg + (size_t)r*Dx + c8*8);
  }
  __syncthreads();

  // hoist Q B-frags (rows = w*32+q32, k(d) = ds*16 + hi*8 + j)
  bf16x8 qf[4];
  #pragma unroll
  for (int ds=0; ds<4; ++ds)
    qf[ds] = *(const bf16x8*)&Qs[w*32 + q32][ds*16 + hi*8];

  // qkp = Qh . kp (unscaled) for own q-row
  float qkp = 0.f;
  #pragma unroll
  for (int ds=0; ds<4; ++ds){
    union { bf16x8 v; unsigned short u[8]; } qa; qa.v = qf[ds];
    #pragma unroll
    for (int j=0;j<8;++j)
      qkp = fmaf(bf2f(qa.u[j]), kp[ds*16 + hi*8 + j], qkp);
  }
  qkp += __shfl_xor(qkp, 32);

  float m_i = -1e30f, l_i = 0.f, a_i = 0.f;
  f32x16 accT[2];
  #pragma unroll
  for (int db=0; db<2; ++db)
    #pragma unroll
    for (int r=0;r<16;++r) accT[db][r] = 0.f;

  const int NT = NKx/64;
  for (int kt = 0; kt < NT; ++kt){
    const int cur = kt & 1;
    const int k0 = kt*64;

    // Kpos for this tile FIRST (so later wait leaves prefetch in flight)
    f32x4 kq[2][4];
    #pragma unroll
    for (int n=0;n<2;++n)
      #pragma unroll
      for (int a=0;a<4;++a)
        kq[n][a] = *(const f32x4*)(KProw + k0 + n*32 + a*8 + hi*4);
    __builtin_amdgcn_sched_barrier(0);

    // prefetch next K/V tile into the other buffer
    if (kt+1 < NT){
      #pragma unroll
      for (int i=0;i<2;++i){
        int r  = i*8 + sr;
        int cs = sc ^ (r & 7);
        gload16(Kg + (size_t)(k0+64 + w*16 + r)*Dx + cs*8,
                (char*)&Kb[cur^1][0][0] + w*2048 + i*1024);
        gload16(Vg + (size_t)(w*16 + r)*NKx + (k0+64) + cs*8,
                (char*)&Vb[cur^1][0][0] + w*2048 + i*1024);
      }
    }
    __builtin_amdgcn_sched_barrier(0);

    // S^T = K . Q^T : rows k' (reg-mapped), cols q (lane&31)
    f32x16 sT[2];
    __builtin_amdgcn_s_setprio(1);
    #pragma unroll
    for (int n=0;n<2;++n){
      f32x16 c;
      #pragma unroll
      for (int r=0;r<16;++r) c[r] = 0.f;
      #pragma unroll
      for (int ds=0; ds<4; ++ds){
        int row = n*32 + q32;
        int cc  = (ds*2 + hi) ^ (q32 & 7);
        bf16x8 kf = *(const bf16x8*)((const char*)&Kb[cur][0][0] + row*128 + cc*16);
        c = __builtin_amdgcn_mfma_f32_32x32x16_bf16(kf, qf[ds], c, 0,0,0);
      }
      sT[n] = c;
    }
    __builtin_amdgcn_s_setprio(0);

    // + Kpos * qkp ; k' = n*32 + (r&3) + 8*(r>>2) + 4*hi
    #pragma unroll
    for (int n=0;n<2;++n)
      #pragma unroll
      for (int r=0;r<16;++r)
        sT[n][r] = fmaf(kq[n][r>>2][r&3], qkp, sT[n][r]);

    // online softmax, own q-row per lane
    float rm = sT[0][0];
    #pragma unroll
    for (int r=1;r<16;++r) rm = fmaxf(rm, sT[0][r]);
    #pragma unroll
    for (int r=0;r<16;++r) rm = fmaxf(rm, sT[1][r]);
    rm = fmaxf(rm, __shfl_xor(rm, 32));

    if (!__all(rm <= m_i + 8.f)){
      float mnew = fmaxf(m_i, rm);
      float al = __expf(m_i - mnew);
      m_i = mnew;
      l_i *= al; a_i *= al;
      #pragma unroll
      for (int db=0; db<2; ++db)
        #pragma unroll
        for (int r=0;r<16;++r) accT[db][r] *= al;
    }

    float ps = 0.f, pk = 0.f;
    #pragma unroll
    for (int n=0;n<2;++n)
      #pragma unroll
      for (int r=0;r<16;++r){
        float p = __expf(sT[n][r] - m_i);
        sT[n][r] = p;
        ps += p;
        pk = fmaf(p, kq[n][r>>2][r&3], pk);
      }
    ps += __shfl_xor(ps, 32);
    pk += __shfl_xor(pk, 32);
    l_i += ps; a_i += pk;

    // pack P to bf16 A-frags in-register: cvt_pk + permlane32_swap
    union PW { unsigned int u[4]; bf16x8 v; } pa[4];
    #pragma unroll
    for (int n=0;n<2;++n){
      unsigned int w0 = cvtpk_bf16(sT[n][0],  sT[n][1]);
      unsigned int w1 = cvtpk_bf16(sT[n][2],  sT[n][3]);
      unsigned int w2 = cvtpk_bf16(sT[n][4],  sT[n][5]);
      unsigned int w3 = cvtpk_bf16(sT[n][6],  sT[n][7]);
      unsigned int w4 = cvtpk_bf16(sT[n][8],  sT[n][9]);
      unsigned int w5 = cvtpk_bf16(sT[n][10], sT[n][11]);
      unsigned int w6 = cvtpk_bf16(sT[n][12], sT[n][13]);
      unsigned int w7 = cvtpk_bf16(sT[n][14], sT[n][15]);
      plane32_swap(w0, w2);
      plane32_swap(w1, w3);
      plane32_swap(w4, w6);
      plane32_swap(w5, w7);
      pa[n*2+0].u[0]=w0; pa[n*2+0].u[1]=w1; pa[n*2+0].u[2]=w2; pa[n*2+0].u[3]=w3;
      pa[n*2+1].u[0]=w4; pa[n*2+1].u[1]=w5; pa[n*2+1].u[2]=w6; pa[n*2+1].u[3]=w7;
    }

    // O^T += V . P : rows d (reg-mapped), cols q (lane&31)
    __builtin_amdgcn_s_setprio(1);
    #pragma unroll
    for (int st=0; st<4; ++st){
      #pragma unroll
      for (int db=0; db<2; ++db){
        int row = db*32 + q32;
        int cc  = (st*2 + hi) ^ (q32 & 7);
        bf16x8 vf = *(const bf16x8*)((const char*)&Vb[cur][0][0] + row*128 + cc*16);
        accT[db] = __builtin_amdgcn_mfma_f32_32x32x16_bf16(vf, pa[st].v, accT[db], 0,0,0);
      }
    }
    __builtin_amdgcn_s_setprio(0);

    __syncthreads();
  }

  // epilogue: X = Qh + O/l + (akp/l)*vp ; d = db*32 + 8a + 4hi + c
  float inv = 1.0f / l_i;
  float aw  = a_i * inv;
  float* Xrow = X + ((size_t)(b*NQx + q0 + w*32 + q32))*Dx + h*64;
  #pragma unroll
  for (int db=0; db<2; ++db){
    #pragma unroll
    for (int a=0; a<4; ++a){
      int d0 = db*32 + a*8 + hi*4;
      f32x4 vpv = *(const f32x4*)(vp + d0);
      float4 o;
      o.x = fmaf(accT[db][a*4+0], inv, bf2f(Qs[w*32+q32][d0+0]) + aw*vpv[0]);
      o.y = fmaf(accT[db][a*4+1], inv, bf2f(Qs[w*32+q32][d0+1]) + aw*vpv[1]);
      o.z = fmaf(accT[db][a*4+2], inv, bf2f(Qs[w*32+q32][d0+2]) + aw*vpv[2]);
      o.w = fmaf(accT[db][a*4+3], inv, bf2f(Qs[w*32+q32][d0+3]) + aw*vpv[3]);
      *(float4*)(Xrow + d0) = o;
    }
  }
}

// ---------------------------------------------------------------------------
// Row LayerNorm over 512; optional secondary bf16 output.
// ---------------------------------------------------------------------------
__global__ __launch_bounds__(256) void mab_ln2(
    const float* __restrict__ Xin, const float* __restrict__ g,
    const float* __restrict__ be, float* __restrict__ Yf, unsigned short* __restrict__ Yb)
{
  const int row = blockIdx.x;
  const int tid = threadIdx.x;
  const float* x = Xin + (size_t)row*Dx;
  float2 v = *(const float2*)(x + tid*2);
  float s  = v.x + v.y;
  float sq = fmaf(v.x,v.x, v.y*v.y);
  #pragma unroll
  for (int m=1; m<64; m<<=1){ s += __shfl_xor(s,m); sq += __shfl_xor(sq,m); }
  __shared__ float red[2][4];
  const int wid = tid>>6, lane = tid&63;
  if (lane==0){ red[0][wid]=s; red[1][wid]=sq; }
  __syncthreads();
  s  = red[0][0]+red[0][1]+red[0][2]+red[0][3];
  sq = red[1][0]+red[1][1]+red[1][2]+red[1][3];
  float mean = s*(1.0f/Dx);
  float var  = sq*(1.0f/Dx) - mean*mean;
  float rstd = rsqrtf(var + 1e-5f);
  float2 gg = *(const float2*)(g  + tid*2);
  float2 bb = *(const float2*)(be + tid*2);
  float2 o;
  o.x = (v.x-mean)*rstd*gg.x + bb.x;
  o.y = (v.y-mean)*rstd*gg.y + bb.y;
  if (Yf) *(float2*)(Yf + (size_t)row*Dx + tid*2) = o;
  if (Yb){
    ushort2 ob; ob.x = f2bf(o.x); ob.y = f2bf(o.y);
    *(ushort2*)(Yb + (size_t)row*Dx + tid*2) = ob;
  }
}

// ---------------------------------------------------------------------------
extern "C" void kernel_launch(void* const* d_in, const int* in_sizes, int n_in,
                              void* d_out, int out_size, void* d_ws, size_t ws_size,
                              hipStream_t stream)
{
  const float* Q    = (const float*)d_in[0];
  const float* K    = (const float*)d_in[1];
  const float* Kpos = (const float*)d_in[2];
  const float* Wq   = (const float*)d_in[3];
  const float* bq   = (const float*)d_in[4];
  const float* Wk   = (const float*)d_in[5];
  const float* bk   = (const float*)d_in[6];
  const float* Wv   = (const float*)d_in[7];
  const float* bv   = (const float*)d_in[8];
  const float* kp   = (const float*)d_in[9];
  const float* vp   = (const float*)d_in[10];
  const float* W0   = (const float*)d_in[11];
  const float* b0   = (const float*)d_in[12];
  const float* W1   = (const float*)d_in[13];
  const float* b1   = (const float*)d_in[14];
  const float* g0   = (const float*)d_in[15];
  const float* be0  = (const float*)d_in[16];
  const float* g1   = (const float*)d_in[17];
  const float* be1  = (const float*)d_in[18];
  float* out = (float*)d_out;
  char* wsb  = (char*)d_ws;

  const size_t MB = 1024*1024;
  unsigned short* Qp  = (unsigned short*)(wsb);          // 8 MiB  [8192][512] bf16
  unsigned short* Kp  = (unsigned short*)(wsb + 8*MB);   // pre-scaled
  unsigned short* Vp  = (unsigned short*)(wsb + 16*MB);
  float*          O0  = (float*)         (wsb + 24*MB);  // 16 MiB f32
  unsigned short* Qb  = (unsigned short*)(wsb + 40*MB);  // 8 MiB -> Vpt after proj
  unsigned short* Kb  = (unsigned short*)(wsb + 48*MB);  // 8 MiB -> O0b after proj
  unsigned short* Wt  = (unsigned short*)(wsb + 56*MB);  // 2.5 MiB [5][512][512]
  unsigned short* Vpt = Qb;
  unsigned short* O0b = Kb;
  unsigned short* T1  = Vp;

  const float scale = 0.044194173824159216f;   // 1/sqrt(512)
  const size_t ZS = (size_t)8192*512;

  // bf16 conversions of Q, K
  mab_cvt<<<2048, 256, 0, stream>>>(Q, Qb, K, Kb, (8192*512)/4);
  // weight transposes (Wq,Wk,Wv,W0,W1)
  mab_wt<<<dim3(8,8,5), 256, 0, stream>>>(Wq, Wk, Wv, W0, W1, Wt);
  // fused Q/K/V projections (z=0,1,2); Kp scaled by 1/sqrt(512)
  mab_gemm_mfma<<<dim3(4,64,3), 256, 0, stream>>>(
      Qb, Kb, Wt, bq, bk, bv, nullptr, Qp, nullptr, 0, scale, ZS);
  // V transpose to d-major
  mab_vt<<<dim3(32,8,4), 256, 0, stream>>>(Vp, Vpt);
  // fused attention (32x32 swapped structure)
  mab_attn2<<<dim3(16,8,4), 256, 0, stream>>>(Qp, Kp, Vpt, Kpos, kp, vp, out);
  // LN0 -> O0 (f32) + O0b (bf16)
  mab_ln2<<<8192, 256, 0, stream>>>(out, g0, be0, O0, O0b);
  // T1 = relu(O0 @ W0 + b0)  (bf16 out)
  mab_gemm_mfma<<<dim3(4,64,1), 256, 0, stream>>>(
      O0b, nullptr, Wt + (size_t)3*512*512, b0, b0, b0, nullptr, T1, nullptr, 1, 1.0f, 0);
  // out = O0 + relu(T1 @ W1 + b1)  (f32 out)
  mab_gemm_mfma<<<dim3(4,64,1), 256, 0, stream>>>(
      T1, nullptr, Wt + (size_t)4*512*512, b1, b1, b1, O0, nullptr, out, 1, 1.0f, 0);
  // final LN in-place
  mab_ln2<<<8192, 256, 0, stream>>>(out, g1, be1, out, nullptr);
}